// Round 1
// baseline (309.998 us; speedup 1.0000x reference)
//
#include <hip/hip_runtime.h>

// GridSample (bilinear, zeros padding, align_corners=True, pixel-offset grid).
// x:    [N=8, C=64, H=256, W=256] f32
// grid: [N=8, Ho=256, Wo=256, 2]  f32  (dx, dy) pixel offsets
// out:  [N, C, Ho, Wo] f32
//
// Strategy: one thread per spatial location (n, ho, wo). Indices + masked
// weights are channel-invariant, so compute once and loop over C=64 with
// 4 gathers + 1 coalesced store each. Memory-bound: ~272 MB min traffic.

#define N_ 8
#define C_ 64
#define H_ 256
#define W_ 256
#define HO_ 256
#define WO_ 256

__global__ __launch_bounds__(256) void gridsample_kernel(
    const float* __restrict__ x,
    const float2* __restrict__ grid2,   // grid viewed as float2 per location
    float* __restrict__ out)
{
    const int sp = blockIdx.x * blockDim.x + threadIdx.x;  // over N*Ho*Wo
    const int total = N_ * HO_ * WO_;
    if (sp >= total) return;

    const int wo = sp % WO_;
    const int t  = sp / WO_;
    const int ho = t % HO_;
    const int n  = t / HO_;

    const float2 g = grid2[sp];
    const float dx = g.x;
    const float dy = g.y;

    // Replicate the reference fp32 chain exactly:
    // norm = abs*2/(W-1) - 1 ; i = (norm+1)*0.5*(W-1)
    const float absx = dx + (float)wo;
    const float absy = dy + (float)ho;
    const float normx = absx * 2.0f / (float)(W_ - 1) - 1.0f;
    const float normy = absy * 2.0f / (float)(H_ - 1) - 1.0f;
    const float ix = (normx + 1.0f) * 0.5f * (float)(W_ - 1);
    const float iy = (normy + 1.0f) * 0.5f * (float)(H_ - 1);

    const float x0f = floorf(ix);
    const float y0f = floorf(iy);
    const float x1f = x0f + 1.0f;
    const float y1f = y0f + 1.0f;

    const float wx1 = ix - x0f, wx0 = 1.0f - wx1;
    const float wy1 = iy - y0f, wy0 = 1.0f - wy1;

    const bool inx0 = (x0f >= 0.0f) && (x0f <= (float)(W_ - 1));
    const bool inx1 = (x1f >= 0.0f) && (x1f <= (float)(W_ - 1));
    const bool iny0 = (y0f >= 0.0f) && (y0f <= (float)(H_ - 1));
    const bool iny1 = (y1f >= 0.0f) && (y1f <= (float)(H_ - 1));

    const int xi0 = min(max((int)x0f, 0), W_ - 1);
    const int xi1 = min(max((int)x1f, 0), W_ - 1);
    const int yi0 = min(max((int)y0f, 0), H_ - 1);
    const int yi1 = min(max((int)y1f, 0), H_ - 1);

    const float w00 = wy0 * wx0 * ((iny0 && inx0) ? 1.0f : 0.0f);
    const float w01 = wy0 * wx1 * ((iny0 && inx1) ? 1.0f : 0.0f);
    const float w10 = wy1 * wx0 * ((iny1 && inx0) ? 1.0f : 0.0f);
    const float w11 = wy1 * wx1 * ((iny1 && inx1) ? 1.0f : 0.0f);

    const int o00 = yi0 * W_ + xi0;
    const int o01 = yi0 * W_ + xi1;
    const int o10 = yi1 * W_ + xi0;
    const int o11 = yi1 * W_ + xi1;

    const float* __restrict__ xb = x + (size_t)n * C_ * H_ * W_;
    float* __restrict__ ob = out + (size_t)n * C_ * HO_ * WO_ + (size_t)ho * WO_ + wo;

    #pragma unroll 4
    for (int c = 0; c < C_; ++c) {
        const float* __restrict__ xc = xb + (size_t)c * H_ * W_;
        const float v = xc[o00] * w00 + xc[o01] * w01
                      + xc[o10] * w10 + xc[o11] * w11;
        ob[(size_t)c * HO_ * WO_] = v;
    }
}

extern "C" void kernel_launch(void* const* d_in, const int* in_sizes, int n_in,
                              void* d_out, int out_size, void* d_ws, size_t ws_size,
                              hipStream_t stream) {
    const float*  x    = (const float*)d_in[0];
    const float2* grid = (const float2*)d_in[1];
    float*        out  = (float*)d_out;

    const int total = N_ * HO_ * WO_;           // 524288 spatial locations
    const int block = 256;
    const int nblocks = (total + block - 1) / block;  // 2048
    gridsample_kernel<<<nblocks, block, 0, stream>>>(x, grid, out);
}

// Round 2
// 294.122 us; speedup vs baseline: 1.0540x; 1.0540x over previous
//
#include <hip/hip_runtime.h>

// GridSample (bilinear, zeros padding, align_corners=True, pixel-offset grid).
// x:    [N=8, C=64, H=256, W=256] f32
// grid: [N=8, Ho=256, Wo=256, 2]  f32  (dx, dy) pixel offsets
// out:  [N, C, Ho, Wo] f32
//
// v2: L2-locality restructure. Channel loop split into 8 chunks of 8.
// Block = one output row (256 wo) for one (n, c-chunk). blockIdx swizzled so
// each XCD (blockIdx % 8 round-robin) runs all 256 ho-rows of one
// (n, c-chunk) plane concurrently: working set 8 ch x 256KB = 2MB < 4MiB L2,
// so each input row is fetched from HBM ~once (was ~3.2x over-fetch).

#define N_ 8
#define C_ 64
#define H_ 256
#define W_ 256
#define HO_ 256
#define WO_ 256
#define CCH 8          // channels per block
#define NCC (C_ / CCH) // 8 channel chunks

__global__ __launch_bounds__(256) void gridsample_kernel(
    const float* __restrict__ x,
    const float2* __restrict__ grid2,
    float* __restrict__ out)
{
    // Swizzle: XCD k (= blockIdx % 8) gets planes k*8..k*8+7, ho ascending.
    // plane = n*8 + cchunk.  Total blocks = 64 planes * 256 ho = 16384.
    const int b    = blockIdx.x;
    const int xcd  = b & 7;
    const int idx  = b >> 3;                 // 0..2047
    const int plane = xcd * (NCC * N_ / 8) + (idx >> 8); // 8 planes per XCD
    const int ho   = idx & 255;
    const int n    = plane >> 3;             // plane / NCC
    const int cc   = plane & 7;              // plane % NCC
    const int wo   = threadIdx.x;

    const int sp = (n * HO_ + ho) * WO_ + wo;
    const float2 g = grid2[sp];
    const float dx = g.x;
    const float dy = g.y;

    // Replicate the reference fp32 chain exactly.
    const float absx = dx + (float)wo;
    const float absy = dy + (float)ho;
    const float normx = absx * 2.0f / (float)(W_ - 1) - 1.0f;
    const float normy = absy * 2.0f / (float)(H_ - 1) - 1.0f;
    const float ix = (normx + 1.0f) * 0.5f * (float)(W_ - 1);
    const float iy = (normy + 1.0f) * 0.5f * (float)(H_ - 1);

    const float x0f = floorf(ix);
    const float y0f = floorf(iy);
    const float x1f = x0f + 1.0f;
    const float y1f = y0f + 1.0f;

    const float wx1 = ix - x0f, wx0 = 1.0f - wx1;
    const float wy1 = iy - y0f, wy0 = 1.0f - wy1;

    const bool inx0 = (x0f >= 0.0f) && (x0f <= (float)(W_ - 1));
    const bool inx1 = (x1f >= 0.0f) && (x1f <= (float)(W_ - 1));
    const bool iny0 = (y0f >= 0.0f) && (y0f <= (float)(H_ - 1));
    const bool iny1 = (y1f >= 0.0f) && (y1f <= (float)(H_ - 1));

    const int xi0 = min(max((int)x0f, 0), W_ - 1);
    const int xi1 = min(max((int)x1f, 0), W_ - 1);
    const int yi0 = min(max((int)y0f, 0), H_ - 1);
    const int yi1 = min(max((int)y1f, 0), H_ - 1);

    const float w00 = wy0 * wx0 * ((iny0 && inx0) ? 1.0f : 0.0f);
    const float w01 = wy0 * wx1 * ((iny0 && inx1) ? 1.0f : 0.0f);
    const float w10 = wy1 * wx0 * ((iny1 && inx0) ? 1.0f : 0.0f);
    const float w11 = wy1 * wx1 * ((iny1 && inx1) ? 1.0f : 0.0f);

    const int o00 = yi0 * W_ + xi0;
    const int o01 = yi0 * W_ + xi1;
    const int o10 = yi1 * W_ + xi0;
    const int o11 = yi1 * W_ + xi1;

    const int c0 = cc * CCH;
    const float* __restrict__ xb =
        x + ((size_t)n * C_ + c0) * (H_ * W_);
    float* __restrict__ ob =
        out + (((size_t)n * C_ + c0) * HO_ + ho) * WO_ + wo;

    #pragma unroll
    for (int c = 0; c < CCH; ++c) {
        const float* __restrict__ xc = xb + (size_t)c * (H_ * W_);
        const float v = xc[o00] * w00 + xc[o01] * w01
                      + xc[o10] * w10 + xc[o11] * w11;
        ob[(size_t)c * (HO_ * WO_)] = v;
    }
}

extern "C" void kernel_launch(void* const* d_in, const int* in_sizes, int n_in,
                              void* d_out, int out_size, void* d_ws, size_t ws_size,
                              hipStream_t stream) {
    const float*  x    = (const float*)d_in[0];
    const float2* grid = (const float2*)d_in[1];
    float*        out  = (float*)d_out;

    const int nblocks = N_ * NCC * HO_;   // 16384 blocks of 256 threads
    gridsample_kernel<<<nblocks, 256, 0, stream>>>(x, grid, out);
}

// Round 3
// 282.338 us; speedup vs baseline: 1.0980x; 1.0417x over previous
//
#include <hip/hip_runtime.h>

// GridSample (bilinear, zeros padding, align_corners=True, pixel-offset grid).
// x:    [N=8, C=64, H=256, W=256] f32
// grid: [N=8, Ho=256, Wo=256, 2]  f32  (dx, dy) pixel offsets
// out:  [N, C, Ho, Wo] f32
//
// v3: paired-corner gathers. The two x-corners per (row,pixel) are adjacent
// floats -> one global_load_dwordx2 at xlo = clamp(x0, 0, W-2) instead of two
// dword gathers. Clamp/OOB edge cases fold into channel-invariant weights
// (A,B selects), so the per-channel body is 2 dwordx2 gathers + 4 FMA + 1
// store. VMEM instrs/thread: 41 -> 25 (v2 measured ~31 cyc/VMEM instr:
// address-throughput-bound scattered gathers).
// v2's XCD-swizzle kept: FETCH_SIZE 418 MB -> 78 MB.

#define N_ 8
#define C_ 64
#define H_ 256
#define W_ 256
#define HO_ 256
#define WO_ 256
#define CCH 8          // channels per block
#define NCC (C_ / CCH) // 8 channel chunks

typedef float f2v __attribute__((ext_vector_type(2)));

__global__ __launch_bounds__(256) void gridsample_kernel(
    const float* __restrict__ x,
    const float2* __restrict__ grid2,
    float* __restrict__ out)
{
    // XCD k (= blockIdx % 8) gets planes k*8..k*8+7 (plane = (n, c-chunk)),
    // ho ascending: per-XCD working set 8ch x 256KB = 2MB < 4MiB L2.
    const int b    = blockIdx.x;
    const int xcd  = b & 7;
    const int idx  = b >> 3;                 // 0..2047
    const int plane = xcd * (NCC * N_ / 8) + (idx >> 8);
    const int ho   = idx & 255;
    const int n    = plane >> 3;
    const int cc   = plane & 7;
    const int wo   = threadIdx.x;

    const int sp = (n * HO_ + ho) * WO_ + wo;
    const float2 g = grid2[sp];

    // Replicate the reference fp32 chain exactly.
    const float absx = g.x + (float)wo;
    const float absy = g.y + (float)ho;
    const float normx = absx * 2.0f / (float)(W_ - 1) - 1.0f;
    const float normy = absy * 2.0f / (float)(H_ - 1) - 1.0f;
    const float ix = (normx + 1.0f) * 0.5f * (float)(W_ - 1);
    const float iy = (normy + 1.0f) * 0.5f * (float)(H_ - 1);

    const float x0f = floorf(ix);
    const float y0f = floorf(iy);
    const float x1f = x0f + 1.0f;
    const float y1f = y0f + 1.0f;

    const float wx1 = ix - x0f, wx0 = 1.0f - wx1;
    const float wy1 = iy - y0f, wy0 = 1.0f - wy1;

    // Horizontal weights with zero-padding masks.
    const float hx0 = ((x0f >= 0.0f) && (x0f <= (float)(W_ - 1))) ? wx0 : 0.0f;
    const float hx1 = ((x1f >= 0.0f) && (x1f <= (float)(W_ - 1))) ? wx1 : 0.0f;
    // Vertical weights with masks.
    const float ey0 = ((y0f >= 0.0f) && (y0f <= (float)(H_ - 1))) ? wy0 : 0.0f;
    const float ey1 = ((y1f >= 0.0f) && (y1f <= (float)(H_ - 1))) ? wy1 : 0.0f;

    // Pair base column, clamped so the 8B load is always in-bounds.
    const int xlo = (int)fminf(fmaxf(x0f, 0.0f), (float)(W_ - 2));
    // Map corner weights onto the loaded pair {v.x = col xlo, v.y = col xlo+1}:
    //  normal (0<=x0<=W-2): corner0 -> v.x, corner1 -> v.y
    //  x0 == W-1 (clamped): corner0 -> v.y            (corner1 OOB, hx1=0)
    //  x0 == -1:            corner1 -> v.x            (corner0 OOB, hx0=0)
    const bool hi = (x0f >= (float)(W_ - 1));   // corner0 landed on v.y
    const bool lo = (x0f <= -1.0f);             // corner1 landed on v.x
    const float A = (hi ? 0.0f : hx0) + (lo ? hx1 : 0.0f);  // weight of v.x
    const float B = (hi ? hx0 : 0.0f) + (lo ? 0.0f : hx1);  // weight of v.y

    // Channel-invariant final corner weights.
    const float W00 = A * ey0, W01 = B * ey0;
    const float W10 = A * ey1, W11 = B * ey1;

    const int yr0 = min(max((int)y0f, 0), H_ - 1);
    const int yr1 = min(max((int)y1f, 0), H_ - 1);
    const int r0 = yr0 * W_ + xlo;
    const int r1 = yr1 * W_ + xlo;

    const int c0 = cc * CCH;
    const float* __restrict__ xb =
        x + ((size_t)n * C_ + c0) * (H_ * W_);
    float* __restrict__ ob =
        out + (((size_t)n * C_ + c0) * HO_ + ho) * WO_ + wo;

    #pragma unroll
    for (int c = 0; c < CCH; ++c) {
        const float* __restrict__ xc = xb + (size_t)c * (H_ * W_);
        f2v v0, v1;
        __builtin_memcpy(&v0, xc + r0, 8);   // dwordx2, 4B-aligned OK
        __builtin_memcpy(&v1, xc + r1, 8);
        const float val = v0.x * W00 + v0.y * W01
                        + v1.x * W10 + v1.y * W11;
        ob[(size_t)c * (HO_ * WO_)] = val;
    }
}

extern "C" void kernel_launch(void* const* d_in, const int* in_sizes, int n_in,
                              void* d_out, int out_size, void* d_ws, size_t ws_size,
                              hipStream_t stream) {
    const float*  x    = (const float*)d_in[0];
    const float2* grid = (const float2*)d_in[1];
    float*        out  = (float*)d_out;

    const int nblocks = N_ * NCC * HO_;   // 16384 blocks of 256 threads
    gridsample_kernel<<<nblocks, 256, 0, stream>>>(x, grid, out);
}